// Round 17
// baseline (46.903 us; speedup 1.0000x reference)
//
#include <hip/hip_runtime.h>

#define NQ     14
#define DIM    16384
#define NPAR   196
#define NCLS   10
#define NGT    42     // U2 (14) + U3 (14) + U4 (14); layers 0-1 + chains 0-1 in TT init
#define PH1    33     // kernel-0 gates: U2[13..2] + U3[13..3] + U4[13..4]
#define NCOEF  70     // all 70 coefficient sets (chi=2 init uses slots 0..27)

// ---------------- compile-time gate tables (no sigma; commutation-verified) ----------------
// Stored state d[h] = s_ref[h] after the chi=2 TT init (verified r13):
//   d[h] = C1*U1*C0*U0|0> via  sum_j prod_bp V_bp[gh_bp,j_bp] phi_bp[j_bp^j_{bp+1}]
// Remaining circuit: U2, C2, U3, C3, U4.  Chains absorbed into the frame:
//   U2: m=u=e_bp;  U3: m=e_bp^e_{bp-1}, u=suffix-xor;  U4: m,u retabbed again;
//   measurement masks mu[q] = final u[13-q].
// Split (layout choice): kernel 0 local bits h{13..2} (p = h{1,0}); kernel 1
// local bits h{11..0} (p' = h{13,12}).  Phase 1 = gates with (m&3)==0, circuit
// order; phase 2 = the rest (must have (m&0x3000)==0), run after.  Every
// (phase-2 d, later phase-1 g) pair is verified to commute at COMPILE TIME via
// the Pauli-frame criterion: par(m_d&u_g)==0 && par(m_g&u_d)==0  (r15 lesson).
struct GateInfo { int m; int u; int slot; };
struct Tables { GateInfo g[NGT]; int mu[NQ]; int ph1; bool valid; };

constexpr int par2(unsigned v) { int c = 0; while (v) { c ^= 1; v &= v - 1; } return c; }

constexpr Tables make_tables() {
    Tables T{};
    T.valid = true;
    unsigned cm[NQ] = {}, cu[NQ] = {};
    for (int i = 0; i < NQ; ++i) { cm[i] = 1u << i; cu[i] = 1u << i; }
    GateInfo all[3][NQ] = {};
    for (int L = 0; L < 3; ++L) {                 // L=0:U2, 1:U3, 2:U4
        for (int q = 0; q < NQ; ++q) {
            int bp = 13 - q;
            all[L][q].m = (int)cm[bp]; all[L][q].u = (int)cu[bp];
            all[L][q].slot = 28 + 14 * L + q;
        }
        if (L < 2) {                              // chains C2, C3
            for (int bp = 13; bp >= 1; --bp) cm[bp] ^= cm[bp - 1];
            unsigned acc = 0;
            for (int bp = 13; bp >= 0; --bp) { acc ^= cu[bp]; cu[bp] = acc; }
        }
    }
    for (int q = 0; q < NQ; ++q) T.mu[q] = (int)cu[13 - q];
    GateInfo p2[NGT] = {};
    int n1 = 0, n2 = 0;
    for (int L = 0; L < 3; ++L)
        for (int q = 0; q < NQ; ++q) {
            GateInfo gi = all[L][q];
            if ((gi.m & 0x3) == 0) {              // kernel-0 local
                for (int i = 0; i < n2; ++i)      // must commute w/ earlier deferred
                    if (par2(p2[i].m & gi.u) || par2(gi.m & p2[i].u)) T.valid = false;
                T.g[n1++] = gi;
            } else {
                if (gi.m & 0x3000) T.valid = false;   // kernel-1 local required
                p2[n2++] = gi;
            }
        }
    T.ph1 = n1;
    if (n1 != PH1 || n1 + n2 != NGT) T.valid = false;
    for (int i = 0; i < n2; ++i) T.g[PH1 + i] = p2[i];
    return T;
}
constexpr Tables TAB = make_tables();
static_assert(TAB.valid, "gate schedule construction failed");
static_assert(TAB.ph1 == PH1, "phase-1 count");

// ---- chi=2 TT helpers (verified r13). site bp: V = U1 gate (uc[14+q]), phi =
// col0 of U0 gate (uc[q]), q = 13-bp, j_14 = 0.
__device__ __forceinline__ void tt_step(float& r0r, float& r0i, float& r1r, float& r1i,
                                        const float* Vu, const float* Pu, int ghb)
{
    const float v0r = Vu[ghb * 4 + 0], v0i = Vu[ghb * 4 + 1];
    const float v1r = Vu[ghb * 4 + 2], v1i = Vu[ghb * 4 + 3];
    const float Ar = v0r * r0r - v0i * r0i, Ai = v0r * r0i + v0i * r0r;
    const float Br = v1r * r1r - v1i * r1i, Bi = v1r * r1i + v1i * r1r;
    const float p0r = Pu[0], p0i = Pu[1], p1r = Pu[4], p1i = Pu[5];
    r0r = Ar * p0r - Ai * p0i + Br * p1r - Bi * p1i;
    r0i = Ar * p0i + Ai * p0r + Br * p1i + Bi * p1r;
    r1r = Ar * p1r - Ai * p1i + Br * p0r - Bi * p0i;
    r1i = Ar * p1i + Ai * p1r + Br * p0i + Bi * p0r;
}
__device__ __forceinline__ void tt_wstep(float& w0r, float& w0i, float& w1r, float& w1i,
                                         const float* Vu, const float* Pu, int ghb)
{
    const float p0r = Pu[0], p0i = Pu[1], p1r = Pu[4], p1i = Pu[5];
    const float t0r = p0r * w0r - p0i * w0i + p1r * w1r - p1i * w1i;
    const float t0i = p0r * w0i + p0i * w0r + p1r * w1i + p1i * w1r;
    const float t1r = p1r * w0r - p1i * w0i + p0r * w1r - p0i * w1i;
    const float t1i = p1r * w0i + p1i * w0r + p0r * w1i + p0i * w1r;
    const float v0r = Vu[ghb * 4 + 0], v0i = Vu[ghb * 4 + 1];
    const float v1r = Vu[ghb * 4 + 2], v1i = Vu[ghb * 4 + 3];
    w0r = v0r * t0r - v0i * t0i; w0i = v0r * t0i + v0i * t0r;
    w1r = v1r * t1r - v1i * t1i; w1i = v1r * t1i + v1i * t1r;
}

// Apply this kernel's gate range. Layout-dependent mask decomposition:
//  SEG 0: h = w<<11 | k<<8 | l<<2 | p     (p: blk&3 -> h bits 1,0)
//  SEG 1: h = p<<12 | w<<9 | k2<<8 | l<<2 | k1<<1 | k0
template<int SEG>
__device__ __forceinline__ void do_gates(float (&ar)[8], float (&ai)[8],
    const float (*uc)[8], float* lds_r, float* lds_i, int tid, int hbase)
{
    constexpr int LO = (SEG == 0) ? 0 : PH1;
    constexpr int HI = (SEG == 0) ? PH1 : NGT;
    #pragma unroll
    for (int g = LO; g < HI; ++g) {
        const int m = TAB.g[g].m, u = TAB.g[g].u;
        const int ml = (m >> 2) & 63;
        const int mk = (SEG == 0) ? ((m >> 8) & 7)
                                  : ((((m >> 8) & 1) << 2) | (m & 3));
        const int mw = (SEG == 0) ? ((m >> 11) & 7) : ((m >> 9) & 7);
        const int ku = (SEG == 0) ? ((u >> 8) & 7)
                                  : ((((u >> 8) & 1) << 2) | (u & 3));
        const float4 c0 = *(const float4*)&uc[TAB.g[g].slot][0];  // {00r,00i,01r,01i}
        const float4 c1 = *(const float4*)&uc[TAB.g[g].slot][4];  // {10r,10i,11r,11i}
        const bool rb = (__popc(hbase & u) & 1) != 0;
        const float D0r = rb ? c1.z : c0.x, D0i = rb ? c1.w : c0.y;
        const float O0r = rb ? c1.x : c0.z, O0i = rb ? c1.y : c0.w;
        const float D1r = rb ? c0.x : c1.z, D1i = rb ? c0.y : c1.w;
        const float O1r = rb ? c0.z : c1.x, O1i = rb ? c0.w : c1.y;

        float pr[8], pim[8];
        if (mw == 0 && ml == 0) {
            #pragma unroll
            for (int k = 0; k < 8; ++k) { pr[k] = ar[k ^ mk]; pim[k] = ai[k ^ mk]; }
        } else if (mw == 0) {
            #pragma unroll
            for (int k = 0; k < 8; ++k) {
                pr[k]  = __shfl_xor(ar[k ^ mk], ml, 64);
                pim[k] = __shfl_xor(ai[k ^ mk], ml, 64);
            }
        } else {
            const int tm = (mw << 6) | ml;
            __syncthreads();   // WAR: prior readers of lds done
            #pragma unroll
            for (int k = 0; k < 8; ++k) {
                lds_r[k * 512 + tid] = ar[k];
                lds_i[k * 512 + tid] = ai[k];
            }
            __syncthreads();
            #pragma unroll
            for (int k = 0; k < 8; ++k) {
                pr[k]  = lds_r[(k ^ mk) * 512 + (tid ^ tm)];
                pim[k] = lds_i[(k ^ mk) * 512 + (tid ^ tm)];
            }
        }
        #pragma unroll
        for (int k = 0; k < 8; ++k) {
            const int cls = __popc(k & ku) & 1;   // compile-time per k
            const float Dr = cls ? D1r : D0r, Di = cls ? D1i : D0i;
            const float Or = cls ? O1r : O0r, Oi = cls ? O1i : O0i;
            float nr = Dr * ar[k] - Di * ai[k] + Or * pr[k] - Oi * pim[k];
            float ni = Dr * ai[k] + Di * ar[k] + Or * pim[k] + Oi * pr[k];
            ar[k] = nr; ai[k] = ni;
        }
    }
}

// ============ 2 kernels: 256 blocks x 512 threads, A = 8 ============
// Buffer index b(h) = h{7..2} | h{13..8}<<6 | h{1,0}<<12  (+ e<<14)  (verified r16):
//  k0 store: b = l | ((w<<3)|k)<<6 | p<<12                      -> unit stride in l
//  k1 load:  b = l | ((p<<4)|(w<<1)|(k>>2))<<6 | (k&3)<<12     -> unit stride in l
template<int SEG>
__global__ void __launch_bounds__(512)
qvc_seg(const float* __restrict__ x, const float2* __restrict__ gin,
        float2* __restrict__ gout, const float* __restrict__ W,
        const float* __restrict__ bias, float* __restrict__ out)
{
    __shared__ __align__(16) float uc[NCOEF][8];
    __shared__ float lds_r[SEG == 0 ? 8 * 512 : 64];
    __shared__ float lds_i[SEG == 0 ? 8 * 512 : 64];
    __shared__ float red[8][NQ];
    __shared__ float eqv[NQ];

    const int blk = blockIdx.x;
    const int e = blk >> 2, p = blk & 3;
    const int tid = threadIdx.x;
    const int w = tid >> 6, l = tid & 63;
    const int hbase = (SEG == 0) ? ((w << 11) | (l << 2) | p)       // k bits 8..10 zero
                                 : ((p << 12) | (w << 9) | (l << 2)); // k' bits 8,1,0 zero
    const float* xb = x + e * NPAR;

    if constexpr (SEG == 0) {           // zero out before SEG1's atomics (stream order)
        if (blk == 0)
            for (int t = tid; t < 64 * NCLS; t += 512) out[t] = 0.0f;
    }

    // ---- all 70 gate-coefficient sets, one per thread ----
    if (tid < NCOEF) {
        const int layer = tid / 14, q = tid % 14;
        const int pidx = (layer < 4) ? layer * 42 + q * 3 : 168 + q * 2;
        float a1 = 0.5f * xb[pidx], a2 = 0.5f * xb[pidx + 1];
        float s1, c1, s2, c2;
        sincosf(a1, &s1, &c1);
        sincosf(a2, &s2, &c2);
        float A00r =  c2 * c1, A00i =  s2 * s1;
        float A01r = -s2 * c1, A01i = -c2 * s1;
        float A10r =  s2 * c1, A10i = -c2 * s1;
        float A11r =  c2 * c1, A11i = -s2 * s1;
        float U0, U1, U2, U3, U4, U5, U6, U7;
        if (layer < 4) {
            float a3 = 0.5f * xb[pidx + 2]; float s3, c3; sincosf(a3, &s3, &c3);
            U0 = c3 * A00r + s3 * A00i; U1 = c3 * A00i - s3 * A00r;
            U2 = c3 * A01r + s3 * A01i; U3 = c3 * A01i - s3 * A01r;
            U4 = c3 * A10r - s3 * A10i; U5 = c3 * A10i + s3 * A10r;
            U6 = c3 * A11r - s3 * A11i; U7 = c3 * A11i + s3 * A11r;
        } else {
            U0 = A00r; U1 = A00i; U2 = A01r; U3 = A01i;
            U4 = A10r; U5 = A10i; U6 = A11r; U7 = A11i;
        }
        uc[tid][0] = U0; uc[tid][1] = U1; uc[tid][2] = U2; uc[tid][3] = U3;
        uc[tid][4] = U4; uc[tid][5] = U5; uc[tid][6] = U6; uc[tid][7] = U7;
    }
    __syncthreads();

    float ar[8], ai[8];
    if constexpr (SEG == 0) {
        // ---- chi=2 TT init (helpers verified r13), partitioned for this layout:
        // shared prefix sites 0..6; per-k middle 7..10 (k = h bits 8..10);
        // suffix base site 13 + wsteps 12, 11.
        const int ghs = hbase ^ (hbase >> 1);     // bits 0..6, 11..13 k-independent
        float R0r = 1.0f, R0i = 0.0f, R1r = 1.0f, R1i = 0.0f;
        #pragma unroll
        for (int bp = 0; bp < 7; ++bp)
            tt_step(R0r, R0i, R1r, R1i, &uc[14 + (13 - bp)][0], &uc[13 - bp][0],
                    (ghs >> bp) & 1);
        float W0r, W0i, W1r, W1i;
        {
            const int b13 = (ghs >> 13) & 1;
            const float* Vu = &uc[14 + 0][0];     // site 13 -> q = 0
            const float* Pu = &uc[0][0];
            const float v0r = Vu[b13 * 4 + 0], v0i = Vu[b13 * 4 + 1];
            const float v1r = Vu[b13 * 4 + 2], v1i = Vu[b13 * 4 + 3];
            W0r = v0r * Pu[0] - v0i * Pu[1]; W0i = v0r * Pu[1] + v0i * Pu[0];
            W1r = v1r * Pu[4] - v1i * Pu[5]; W1i = v1r * Pu[5] + v1i * Pu[4];
        }
        #pragma unroll
        for (int bp = 12; bp >= 11; --bp)
            tt_wstep(W0r, W0i, W1r, W1i, &uc[14 + (13 - bp)][0], &uc[13 - bp][0],
                     (ghs >> bp) & 1);
        #pragma unroll
        for (int k = 0; k < 8; ++k) {
            const int hh = hbase | (k << 8);
            const int ghk = hh ^ (hh >> 1);
            float r0r = R0r, r0i = R0i, r1r = R1r, r1i = R1i;
            #pragma unroll
            for (int bp = 7; bp <= 10; ++bp)
                tt_step(r0r, r0i, r1r, r1i, &uc[14 + (13 - bp)][0], &uc[13 - bp][0],
                        (ghk >> bp) & 1);
            ar[k] = r0r * W0r - r0i * W0i + r1r * W1r - r1i * W1i;
            ai[k] = r0r * W0i + r0i * W0r + r1r * W1i + r1i * W1r;
        }
    } else {
        #pragma unroll
        for (int k = 0; k < 8; ++k) {
            const int idx = (e << 14) | ((k & 3) << 12)
                          | (((p << 4) | (w << 1) | (k >> 2)) << 6) | l;
            float2 v = gin[idx];
            ar[k] = v.x; ai[k] = v.y;
        }
    }

    do_gates<SEG>(ar, ai, uc, lds_r, lds_i, tid, hbase);

    if constexpr (SEG == 0) {
        #pragma unroll
        for (int k = 0; k < 8; ++k) {
            const int idx = (e << 14) | (p << 12) | (((w << 3) | k) << 6) | l;
            gout[idx] = make_float2(ar[k], ai[k]);
        }
    } else {
        // ---- measurement: E_q = sum |amp|^2 * (-1)^parity(h & mu[q]) ----
        float eq[NQ];
        #pragma unroll
        for (int q = 0; q < NQ; ++q) eq[q] = 0.0f;
        #pragma unroll
        for (int k = 0; k < 8; ++k) {
            float p2v = ar[k] * ar[k] + ai[k] * ai[k];
            #pragma unroll
            for (int q = 0; q < NQ; ++q) {
                const int kmu = (((TAB.mu[q] >> 8) & 1) << 2) | (TAB.mu[q] & 3);
                if (__popc(k & kmu) & 1) eq[q] -= p2v; else eq[q] += p2v;
            }
        }
        #pragma unroll
        for (int q = 0; q < NQ; ++q) {
            float v = (__popc(hbase & TAB.mu[q]) & 1) ? -eq[q] : eq[q];
            #pragma unroll
            for (int off = 32; off > 0; off >>= 1) v += __shfl_down(v, off, 64);
            eq[q] = v;
        }
        if (l == 0) {
            #pragma unroll
            for (int q = 0; q < NQ; ++q) red[w][q] = eq[q];
        }
        __syncthreads();
        if (tid < NQ) {
            float s = 0.0f;
            #pragma unroll
            for (int ww = 0; ww < 8; ++ww) s += red[ww][tid];
            eqv[tid] = s;
        }
        __syncthreads();
        // ---- head folded in: atomicAdd partial dot products (out zeroed in SEG 0) ----
        if (tid < NCLS) {
            float acc = (p == 0) ? bias[tid] : 0.0f;
            #pragma unroll
            for (int q = 0; q < NQ; ++q) acc += W[tid * NQ + q] * eqv[q];
            atomicAdd(&out[e * NCLS + tid], acc);   // device-scope, cross-XCD safe
        }
    }
}

extern "C" void kernel_launch(void* const* d_in, const int* in_sizes, int n_in,
                              void* d_out, int out_size, void* d_ws, size_t ws_size,
                              hipStream_t stream)
{
    const float* x    = (const float*)d_in[0];   // (64, 196)
    const float* W    = (const float*)d_in[1];   // (10, 14)
    const float* bias = (const float*)d_in[2];   // (10,)
    float*       out  = (float*)d_out;           // (64, 10)

    float2* bufA = (float2*)d_ws;                // one 8 MB state buffer
    (void)ws_size;  // observed 268 MB >> 8 MB needed

    hipLaunchKernelGGL(qvc_seg<0>, dim3(256), dim3(512), 0, stream,
                       x, (const float2*)nullptr, bufA, W, bias, out);
    hipLaunchKernelGGL(qvc_seg<1>, dim3(256), dim3(512), 0, stream,
                       x, bufA, (float2*)nullptr, W, bias, out);
}

// Round 18
// 37.545 us; speedup vs baseline: 1.2493x; 1.2493x over previous
//
#include <hip/hip_runtime.h>

#define NQ     14
#define DIM    16384
#define NPAR   196
#define NCLS   10
#define NGT    28     // U3 (14) + U4 (14); layers 0-2 + chains 0-2 in TT init
#define PH1    23     // kernel-0 gates: U3[13..2] (12) + U4[13..3] (11)
#define NCOEF  70     // all 70 coefficient sets (init uses slots 0..41)

// ---------------- compile-time gate tables (verified r16 on HW) ----------------
// Stored state d[h] = s_ref[A(h)].  After the chi=4 TT init, A = I.
// Remaining: U3 (m3=u3=e_bp), chain C3 absorbed (m4[j]=e_j^e_{j-1}, u4[j]=
// e13^..^e_j), measurement masks mu[q]=u4[13-q].
// Commutation criterion: (mA,uA),(mB,uB) commute iff par(mA&uB)==0 && par(mB&uA)==0.
// Split (layout choice): kernel 0 local bits h{13..2} (p = h{1,0}); kernel 1
// local bits h{11..0} (p' = h{13,12}).
struct GateInfo { int m; int u; int slot; };
struct Tables { GateInfo g[NGT]; int mu[NQ]; bool valid; };

constexpr Tables make_tables() {
    Tables T{};
    T.valid = true;
    int gi = 0;
    for (int bp = 13; bp >= 2; --bp) {           // phase 1: U3
        T.g[gi].m = 1 << bp; T.g[gi].u = 1 << bp;
        T.g[gi].slot = 42 + (13 - bp); ++gi;
    }
    for (int j = 13; j >= 3; --j) {              // phase 1: U4 (preds all done)
        T.g[gi].m = (1 << j) | (1 << (j - 1));
        T.g[gi].u = 0x3FFF & ~((1 << j) - 1);
        T.g[gi].slot = 56 + (13 - j); ++gi;
    }
    if (gi != PH1) T.valid = false;
    T.g[gi].m = 2; T.g[gi].u = 2;               T.g[gi].slot = 42 + 12; ++gi; // U3[1]
    T.g[gi].m = 1; T.g[gi].u = 1;               T.g[gi].slot = 42 + 13; ++gi; // U3[0]
    T.g[gi].m = 6; T.g[gi].u = 0x3FFF & ~3;     T.g[gi].slot = 56 + 11; ++gi; // U4[2]
    T.g[gi].m = 3; T.g[gi].u = 0x3FFF & ~1;     T.g[gi].slot = 56 + 12; ++gi; // U4[1]
    T.g[gi].m = 1; T.g[gi].u = 0x3FFF;          T.g[gi].slot = 56 + 13; ++gi; // U4[0]
    if (gi != NGT) T.valid = false;
    for (int i = 0; i < PH1; ++i)   if (T.g[i].m & 0x0003) T.valid = false;  // k0 p-bits
    for (int i = PH1; i < NGT; ++i) if (T.g[i].m & 0x3000) T.valid = false;  // k1 p-bits
    for (int q = 0; q < NQ; ++q) T.mu[q] = 0x3FFF & ~((1 << (13 - q)) - 1);
    return T;
}
constexpr Tables TAB = make_tables();
static_assert(TAB.valid, "gate schedule construction failed");

// ---- 4x4 complex matvec helpers (M row-major 16 float2 in LDS) ----
__device__ __forceinline__ void mv4(const float2* M, const float (&xr)[4],
    const float (&xi)[4], float (&yr)[4], float (&yi)[4])
{
    #pragma unroll
    for (int r = 0; r < 4; ++r) {
        float sr = 0.0f, si = 0.0f;
        #pragma unroll
        for (int c = 0; c < 4; ++c) {
            const float2 m = M[r * 4 + c];
            sr += m.x * xr[c] - m.y * xi[c];
            si += m.x * xi[c] + m.y * xr[c];
        }
        yr[r] = sr; yi[r] = si;
    }
}
__device__ __forceinline__ void mv4t(const float2* M, const float (&xr)[4],
    const float (&xi)[4], float (&yr)[4], float (&yi)[4])
{
    #pragma unroll
    for (int c = 0; c < 4; ++c) {
        float sr = 0.0f, si = 0.0f;
        #pragma unroll
        for (int r = 0; r < 4; ++r) {
            const float2 m = M[r * 4 + c];
            sr += m.x * xr[r] - m.y * xi[r];
            si += m.x * xi[r] + m.y * xr[r];
        }
        yr[c] = sr; yi[c] = si;
    }
}

// Apply this kernel's gate range. Layout-dependent mask decomposition:
//  SEG 0: h = w<<11 | k<<8 | l<<2 | p     (p: blk&3 -> h bits 1,0)
//  SEG 1: h = p<<12 | w<<9 | k2<<8 | l<<2 | k1<<1 | k0
template<int SEG>
__device__ __forceinline__ void do_gates(float (&ar)[8], float (&ai)[8],
    const float (*uc)[8], float* lds_r, float* lds_i, int tid, int hbase)
{
    constexpr int LO = (SEG == 0) ? 0 : PH1;
    constexpr int HI = (SEG == 0) ? PH1 : NGT;
    #pragma unroll
    for (int g = LO; g < HI; ++g) {
        const int m = TAB.g[g].m, u = TAB.g[g].u;
        const int ml = (m >> 2) & 63;
        const int mk = (SEG == 0) ? ((m >> 8) & 7)
                                  : ((((m >> 8) & 1) << 2) | (m & 3));
        const int mw = (SEG == 0) ? ((m >> 11) & 7) : ((m >> 9) & 7);
        const int ku = (SEG == 0) ? ((u >> 8) & 7)
                                  : ((((u >> 8) & 1) << 2) | (u & 3));
        const float4 c0 = *(const float4*)&uc[TAB.g[g].slot][0];  // {00r,00i,01r,01i}
        const float4 c1 = *(const float4*)&uc[TAB.g[g].slot][4];  // {10r,10i,11r,11i}
        const bool rb = (__popc(hbase & u) & 1) != 0;
        const float D0r = rb ? c1.z : c0.x, D0i = rb ? c1.w : c0.y;
        const float O0r = rb ? c1.x : c0.z, O0i = rb ? c1.y : c0.w;
        const float D1r = rb ? c0.x : c1.z, D1i = rb ? c0.y : c1.w;
        const float O1r = rb ? c0.z : c1.x, O1i = rb ? c0.w : c1.y;

        float pr[8], pim[8];
        if (mw == 0 && ml == 0) {
            #pragma unroll
            for (int k = 0; k < 8; ++k) { pr[k] = ar[k ^ mk]; pim[k] = ai[k ^ mk]; }
        } else if (mw == 0) {
            #pragma unroll
            for (int k = 0; k < 8; ++k) {
                pr[k]  = __shfl_xor(ar[k ^ mk], ml, 64);
                pim[k] = __shfl_xor(ai[k ^ mk], ml, 64);
            }
        } else {
            const int tm = (mw << 6) | ml;
            __syncthreads();   // WAR: prior readers of lds done
            #pragma unroll
            for (int k = 0; k < 8; ++k) {
                lds_r[k * 512 + tid] = ar[k];
                lds_i[k * 512 + tid] = ai[k];
            }
            __syncthreads();
            #pragma unroll
            for (int k = 0; k < 8; ++k) {
                pr[k]  = lds_r[(k ^ mk) * 512 + (tid ^ tm)];
                pim[k] = lds_i[(k ^ mk) * 512 + (tid ^ tm)];
            }
        }
        #pragma unroll
        for (int k = 0; k < 8; ++k) {
            const int cls = __popc(k & ku) & 1;   // compile-time per k
            const float Dr = cls ? D1r : D0r, Di = cls ? D1i : D0i;
            const float Or = cls ? O1r : O0r, Oi = cls ? O1i : O0i;
            float nr = Dr * ar[k] - Di * ai[k] + Or * pr[k] - Oi * pim[k];
            float ni = Dr * ai[k] + Di * ar[k] + Or * pim[k] + Oi * pr[k];
            ar[k] = nr; ai[k] = ni;
        }
    }
}

// ============ 2 kernels: 256 blocks x 512 threads, A = 8 ============
// Buffer index b(h) = h{7..2} | h{13..8}<<6 | h{1,0}<<12  (+ e<<14)  (verified r16)
template<int SEG>
__global__ void __launch_bounds__(512)
qvc_seg(const float* __restrict__ x, const float2* __restrict__ gin,
        float2* __restrict__ gout, const float* __restrict__ W,
        const float* __restrict__ bias, float* __restrict__ out)
{
    __shared__ __align__(16) float uc[NCOEF][8];
    __shared__ float lds_r[SEG == 0 ? 8 * 512 : 64];
    __shared__ float lds_i[SEG == 0 ? 8 * 512 : 64];
    __shared__ float2 Msite[SEG == 0 ? 14 * 2 * 16 : 1];  // [site][b][row*4+col]
    __shared__ float2 PPm[SEG == 0 ? 6 * 4 * 16 : 1];     // [pair][bb][row*4+col]
    __shared__ float red[8][NQ];
    __shared__ float eqv[NQ];

    const int blk = blockIdx.x;
    const int e = blk >> 2, p = blk & 3;
    const int tid = threadIdx.x;
    const int w = tid >> 6, l = tid & 63;
    const int hbase = (SEG == 0) ? ((w << 11) | (l << 2) | p)
                                 : ((p << 12) | (w << 9) | (l << 2));
    const float* xb = x + e * NPAR;

    if constexpr (SEG == 0) {           // zero out before SEG1's atomics (stream order)
        if (blk == 0)
            for (int t = tid; t < 64 * NCLS; t += 512) out[t] = 0.0f;
    }

    // ---- all 70 gate-coefficient sets, one per thread ----
    if (tid < NCOEF) {
        const int layer = tid / 14, q = tid % 14;
        const int pidx = (layer < 4) ? layer * 42 + q * 3 : 168 + q * 2;
        float a1 = 0.5f * xb[pidx], a2 = 0.5f * xb[pidx + 1];
        float s1, c1, s2, c2;
        sincosf(a1, &s1, &c1);
        sincosf(a2, &s2, &c2);
        float A00r =  c2 * c1, A00i =  s2 * s1;
        float A01r = -s2 * c1, A01i = -c2 * s1;
        float A10r =  s2 * c1, A10i = -c2 * s1;
        float A11r =  c2 * c1, A11i = -s2 * s1;
        float U0, U1, U2, U3, U4, U5, U6, U7;
        if (layer < 4) {
            float a3 = 0.5f * xb[pidx + 2]; float s3, c3; sincosf(a3, &s3, &c3);
            U0 = c3 * A00r + s3 * A00i; U1 = c3 * A00i - s3 * A00r;
            U2 = c3 * A01r + s3 * A01i; U3 = c3 * A01i - s3 * A01r;
            U4 = c3 * A10r - s3 * A10i; U5 = c3 * A10i + s3 * A10r;
            U6 = c3 * A11r - s3 * A11i; U7 = c3 * A11i + s3 * A11r;
        } else {
            U0 = A00r; U1 = A00i; U2 = A01r; U3 = A01i;
            U4 = A10r; U5 = A10i; U6 = A11r; U7 = A11i;
        }
        uc[tid][0] = U0; uc[tid][1] = U1; uc[tid][2] = U2; uc[tid][3] = U3;
        uc[tid][4] = U4; uc[tid][5] = U5; uc[tid][6] = U6; uc[tid][7] = U7;
    }
    __syncthreads();

    float ar[8], ai[8];
    if constexpr (SEG == 0) {
        // ---- stage 1: per-site 4x4 matrices (from the r14-verified tt4_step):
        // M_s(b)[(c2p,cp)][(c2,c)] = V2[b,c2] * V1[c2^c2p, c] * phi[c^cp]
        if (tid < 448) {
            const int s = tid >> 5, b = (tid >> 4) & 1, eidx = tid & 15;
            const int row = eidx >> 2, col = eidx & 3;
            const int c2p = row >> 1, cp = row & 1, c2 = col >> 1, c = col & 1;
            const int q = 13 - s;
            const float* V2 = &uc[28 + q][0];
            const float* V1 = &uc[14 + q][0];
            const float* Ph = &uc[q][0];
            const float v2r = V2[b * 4 + c2 * 2],        v2i = V2[b * 4 + c2 * 2 + 1];
            const float v1r = V1[(c2 ^ c2p) * 4 + c * 2], v1i = V1[(c2 ^ c2p) * 4 + c * 2 + 1];
            const float phr = Ph[(c ^ cp) * 4],          phi_ = Ph[(c ^ cp) * 4 + 1];
            const float t1r = v2r * v1r - v2i * v1i, t1i = v2r * v1i + v2i * v1r;
            Msite[(s * 2 + b) * 16 + eidx] =
                make_float2(t1r * phr - t1i * phi_, t1r * phi_ + t1i * phr);
        }
        __syncthreads();
        // ---- stage 2: pair products PP = M_hi * M_lo over
        // pairs {(0,1),(2,3),(4,5),(7,8),(9,10),(11,12)}, 4 bit-combos each
        if (tid < 384) {
            const int pr = tid >> 6, bb = (tid >> 4) & 3, eidx = tid & 15;
            const int row = eidx >> 2, col = eidx & 3;
            const int lo = 2 * pr + (pr >= 3 ? 1 : 0);
            float sr = 0.0f, si = 0.0f;
            #pragma unroll
            for (int mm = 0; mm < 4; ++mm) {
                const float2 a = Msite[((lo + 1) * 2 + (bb >> 1)) * 16 + row * 4 + mm];
                const float2 bmat = Msite[(lo * 2 + (bb & 1)) * 16 + mm * 4 + col];
                sr += a.x * bmat.x - a.y * bmat.y;
                si += a.x * bmat.y + a.y * bmat.x;
            }
            PPm[(pr * 4 + bb) * 16 + eidx] = make_float2(sr, si);
        }
        __syncthreads();
        // ---- init eval: prefix sites 0..6, per-k 7..10, suffix 11..13 ----
        const int ghs = hbase ^ (hbase >> 1);     // bits 0..6, 11..13 k-independent
        float Rr[4] = {1,1,1,1}, Ri[4] = {0,0,0,0}, Tr[4], Ti[4];
        mv4(&PPm[(0 * 4 + (ghs & 3)) * 16],        Rr, Ri, Tr, Ti);   // sites 0,1
        mv4(&PPm[(1 * 4 + ((ghs >> 2) & 3)) * 16], Tr, Ti, Rr, Ri);   // sites 2,3
        mv4(&PPm[(2 * 4 + ((ghs >> 4) & 3)) * 16], Rr, Ri, Tr, Ti);   // sites 4,5
        mv4(&Msite[(6 * 2 + ((ghs >> 6) & 1)) * 16], Tr, Ti, Rr, Ri); // site 6
        // suffix: W13 = row 0 of M13(b13); W = PP(11,12)^T * W13
        float W13r[4], W13i[4], Wr_[4], Wi_[4];
        {
            const int b13 = (ghs >> 13) & 1;
            #pragma unroll
            for (int c = 0; c < 4; ++c) {
                const float2 mm2 = Msite[(13 * 2 + b13) * 16 + c];  // row 0
                W13r[c] = mm2.x; W13i[c] = mm2.y;
            }
        }
        mv4t(&PPm[(5 * 4 + ((ghs >> 11) & 3)) * 16], W13r, W13i, Wr_, Wi_);
        // per-k: sites (7,8),(9,10) then dot
        #pragma unroll
        for (int k = 0; k < 8; ++k) {
            const int hh = hbase | (k << 8);
            const int ghk = hh ^ (hh >> 1);
            float Sr[4], Si[4];
            mv4(&PPm[(3 * 4 + ((ghk >> 7) & 3)) * 16], Rr, Ri, Tr, Ti);
            mv4(&PPm[(4 * 4 + ((ghk >> 9) & 3)) * 16], Tr, Ti, Sr, Si);
            float dr = 0.0f, di = 0.0f;
            #pragma unroll
            for (int j = 0; j < 4; ++j) {
                dr += Sr[j] * Wr_[j] - Si[j] * Wi_[j];
                di += Sr[j] * Wi_[j] + Si[j] * Wr_[j];
            }
            ar[k] = dr; ai[k] = di;
        }
    } else {
        #pragma unroll
        for (int k = 0; k < 8; ++k) {
            const int idx = (e << 14) | ((k & 3) << 12)
                          | (((p << 4) | (w << 1) | (k >> 2)) << 6) | l;
            float2 v = gin[idx];
            ar[k] = v.x; ai[k] = v.y;
        }
    }

    do_gates<SEG>(ar, ai, uc, lds_r, lds_i, tid, hbase);

    if constexpr (SEG == 0) {
        #pragma unroll
        for (int k = 0; k < 8; ++k) {
            const int idx = (e << 14) | (p << 12) | (((w << 3) | k) << 6) | l;
            gout[idx] = make_float2(ar[k], ai[k]);
        }
    } else {
        // ---- measurement: E_q = sum |amp|^2 * (-1)^parity(h & mu[q]) ----
        float eq[NQ];
        #pragma unroll
        for (int q = 0; q < NQ; ++q) eq[q] = 0.0f;
        #pragma unroll
        for (int k = 0; k < 8; ++k) {
            float p2v = ar[k] * ar[k] + ai[k] * ai[k];
            #pragma unroll
            for (int q = 0; q < NQ; ++q) {
                const int kmu = (((TAB.mu[q] >> 8) & 1) << 2) | (TAB.mu[q] & 3);
                if (__popc(k & kmu) & 1) eq[q] -= p2v; else eq[q] += p2v;
            }
        }
        #pragma unroll
        for (int q = 0; q < NQ; ++q) {
            float v = (__popc(hbase & TAB.mu[q]) & 1) ? -eq[q] : eq[q];
            #pragma unroll
            for (int off = 32; off > 0; off >>= 1) v += __shfl_down(v, off, 64);
            eq[q] = v;
        }
        if (l == 0) {
            #pragma unroll
            for (int q = 0; q < NQ; ++q) red[w][q] = eq[q];
        }
        __syncthreads();
        if (tid < NQ) {
            float s = 0.0f;
            #pragma unroll
            for (int ww = 0; ww < 8; ++ww) s += red[ww][tid];
            eqv[tid] = s;
        }
        __syncthreads();
        // ---- head folded in: atomicAdd partial dot products (out zeroed in SEG 0) ----
        if (tid < NCLS) {
            float acc = (p == 0) ? bias[tid] : 0.0f;
            #pragma unroll
            for (int q = 0; q < NQ; ++q) acc += W[tid * NQ + q] * eqv[q];
            atomicAdd(&out[e * NCLS + tid], acc);   // device-scope, cross-XCD safe
        }
    }
}

extern "C" void kernel_launch(void* const* d_in, const int* in_sizes, int n_in,
                              void* d_out, int out_size, void* d_ws, size_t ws_size,
                              hipStream_t stream)
{
    const float* x    = (const float*)d_in[0];   // (64, 196)
    const float* W    = (const float*)d_in[1];   // (10, 14)
    const float* bias = (const float*)d_in[2];   // (10,)
    float*       out  = (float*)d_out;           // (64, 10)

    float2* bufA = (float2*)d_ws;                // one 8 MB state buffer
    (void)ws_size;  // observed 268 MB >> 8 MB needed

    hipLaunchKernelGGL(qvc_seg<0>, dim3(256), dim3(512), 0, stream,
                       x, (const float2*)nullptr, bufA, W, bias, out);
    hipLaunchKernelGGL(qvc_seg<1>, dim3(256), dim3(512), 0, stream,
                       x, bufA, (float2*)nullptr, W, bias, out);
}